// Round 3
// baseline (844.192 us; speedup 1.0000x reference)
//
#include <hip/hip_runtime.h>
#include <hip/hip_bf16.h>

// ---------------------------------------------------------------------------
// Compile-time construction of the 28x8 DWT composition matrix M:
//   y[k] = sum_j M[k][j] * patch[j],  k = [aa(7), ad(7), dd(7), da(7)]
// exactly matching pywt dwt mode='symmetric' applied twice (n=8 then n=7).
// ---------------------------------------------------------------------------
struct M28x8 { float m[28][8]; };

constexpr double DLO[8] = {-0.010597401784997278, 0.032883011666982945,
                            0.030841381835986965, -0.18703481171888114,
                           -0.02798376941698385,   0.6308807679295904,
                            0.7148465705525415,    0.23037781330885523};
constexpr double DHI[8] = {-0.23037781330885523,   0.7148465705525415,
                           -0.6308807679295904,   -0.02798376941698385,
                            0.18703481171888114,   0.030841381835986965,
                           -0.032883011666982945, -0.010597401784997278};

constexpr void dwt_c(const double* x, int n, double* lo, double* hi) {
    int out_len = (n + 7) / 2;
    for (int i = 0; i < out_len; ++i) {
        double a = 0.0, d = 0.0;
        for (int j = 0; j < 8; ++j) {
            int q = 2 * i + j - 6;
            if (q < 0) q = -q - 1;
            if (q >= n) q = 2 * n - 1 - q;
            a += DLO[7 - j] * x[q];
            d += DHI[7 - j] * x[q];
        }
        lo[i] = a; hi[i] = d;
    }
}

constexpr M28x8 build_M() {
    M28x8 R{};
    for (int j = 0; j < 8; ++j) {
        double x[8] = {0,0,0,0,0,0,0,0};
        x[j] = 1.0;
        double cA[7] = {}, cD[7] = {};
        dwt_c(x, 8, cA, cD);
        double aa[7] = {}, ad[7] = {}, da[7] = {}, dd[7] = {};
        dwt_c(cA, 7, aa, ad);
        dwt_c(cD, 7, da, dd);
        for (int i = 0; i < 7; ++i) {
            R.m[i][j]      = (float)aa[i];
            R.m[7 + i][j]  = (float)ad[i];
            R.m[14 + i][j] = (float)dd[i];   // dd before da in concat
            R.m[21 + i][j] = (float)da[i];
        }
    }
    return R;
}

__constant__ M28x8 g_M = build_M();

// ---------------------------------------------------------------------------
// Wfold[o][c*8+j] = sum_k W[o, c*28+k] * M[k][j]   -> 128*24 = 3072 floats
// ---------------------------------------------------------------------------
__global__ void wfold_kernel(const float* __restrict__ W, float* __restrict__ Wf) {
    int t = blockIdx.x * blockDim.x + threadIdx.x;
    if (t >= 128 * 24) return;
    int o = t / 24;
    int cj = t - o * 24;
    int c = cj >> 3;
    int j = cj & 7;
    const float* wr = W + o * 84 + c * 28;
    float acc = 0.f;
#pragma unroll
    for (int k = 0; k < 28; ++k) acc += wr[k] * g_M.m[k][j];
    Wf[t] = acc;
}

// ---------------------------------------------------------------------------
// Main kernel (round-3: lane = (v,pl) pair; weights via scalar cache).
//
//   out[b, v*1024 + p, o] = sum_i Wfold[o][i] * xw[i],  xw = 24-float window
//
// Why: rounds 0-2 broadcast x-windows from LDS to all lanes (o spread across
// lanes) -> 1200-2400 ds_read instrs/block; kernel was LDS-issue-bound.
// This version flips the mapping:
//   * lane owns ONE pair (pl = lane), its 24-float window in VGPRs.
//     One ds_read_b128 loads window data for 64 DIFFERENT pairs -> 6 reads
//     per 64 pairs (vs 6 per 2 pairs). Addresses: base + 16B*lane ->
//     256 consecutive words -> conflict-free, peak LDS rate.
//   * weights are wave-uniform -> compiler emits s_load from scalar cache
//     (Wf = 12 KB, resident in 16 KB sL1) + v_fmac vdst, s_w, v_x.
//     Zero LDS / zero VMEM on the weight path.
//   * stores: per-lane float4, 512 B stride; each lane fills its own 512 B
//     row over 32 chunks -> L2 write-combines (same sector count as
//     coalesced). Wave's 25 v-groups x 32 KB regions.
//   * tile = 64 p, block = 320 thr = 5 waves; wave w handles v = w+5g,
//     g=0..4 -> 25 v-groups perfectly balanced. 512 blocks = exactly 2/CU
//     (LDS 78 KB/block -> 2 resident). ~40 live VGPRs: no spill possible.
// ---------------------------------------------------------------------------
#define PT    64             // p values per block
#define TT    (4 * PT + 4)   // 260 t values
#define SLAB  (3 * 25 * TT)  // 19500 floats = 78 KB LDS

__global__ __launch_bounds__(320, 2) void wave_kernel(const float* __restrict__ x,
                                                      const float* __restrict__ Wf,
                                                      float* __restrict__ out) {
    __shared__ float s_x[SLAB];
    const int tile = blockIdx.x;       // 0..15
    const int b    = blockIdx.y;       // 0..31
    const int t0   = tile * (4 * PT);  // 0,256,...,3840
    const int tid  = threadIdx.x;

    // stage global -> LDS slab [c][v][t] (fully coalesced global reads:
    // lin maps linearly to global offset within each c-segment)
    for (int lin = tid; lin < SLAB; lin += 320) {
        int v  = lin % 25;
        int r  = lin / 25;       // c*TT + tt
        int tt = r % TT;
        int c  = r / TT;
        int t  = t0 + tt;
        if (t > 4095) t = 4095;  // edge padding (PAD=4)
        s_x[(c * 25 + v) * TT + tt] = x[((b * 3 + c) * 4096 + t) * 25 + v];
    }

    const int lane = tid & 63;         // pl = lane (pair within v-group)
    const int wv   = tid >> 6;         // wave id 0..4

    __syncthreads();

    for (int g = 0; g < 5; ++g) {
        const int v = wv + 5 * g;      // 0..24, balanced across waves

        // per-lane 24-float window into VGPRs (conflict-free b128 reads)
        float xw[24];
#pragma unroll
        for (int c = 0; c < 3; ++c) {
            const float4* wp = (const float4*)(s_x + (c * 25 + v) * TT + 4 * lane);
            float4 xa = wp[0];
            float4 xb = wp[1];
            xw[c*8+0] = xa.x; xw[c*8+1] = xa.y; xw[c*8+2] = xa.z; xw[c*8+3] = xa.w;
            xw[c*8+4] = xb.x; xw[c*8+5] = xb.y; xw[c*8+6] = xb.z; xw[c*8+7] = xb.w;
        }

        float* op = out + ((long)(b * 25600 + v * 1024 + tile * PT + lane)) * 128;

        // iterate o in chunks of 4; weights wave-uniform -> scalar loads
        for (int och = 0; och < 32; ++och) {
            const float* wrow = Wf + och * 96;   // uniform address
            float a0 = 0.f, a1 = 0.f, a2 = 0.f, a3 = 0.f;
#pragma unroll
            for (int i = 0; i < 24; ++i) {
                a0 += wrow[i]      * xw[i];
                a1 += wrow[24 + i] * xw[i];
                a2 += wrow[48 + i] * xw[i];
                a3 += wrow[72 + i] * xw[i];
            }
            float4 st = {a0, a1, a2, a3};
            *(float4*)(op + och * 4) = st;
        }
    }
}

extern "C" void kernel_launch(void* const* d_in, const int* in_sizes, int n_in,
                              void* d_out, int out_size, void* d_ws, size_t ws_size,
                              hipStream_t stream) {
    const float* x = (const float*)d_in[0];   // (32, 3, 4096, 25) fp32
    const float* W = (const float*)d_in[1];   // (128, 84) fp32
    float* out = (float*)d_out;               // (32, 25600, 128) fp32
    float* Wf  = (float*)d_ws;                // 3072 floats scratch

    hipLaunchKernelGGL(wfold_kernel, dim3(12), dim3(256), 0, stream, W, Wf);
    hipLaunchKernelGGL(wave_kernel, dim3(16, 32), dim3(320), 0, stream, x, Wf, out);
}

// Round 4
// 475.665 us; speedup vs baseline: 1.7748x; 1.7748x over previous
//
#include <hip/hip_runtime.h>
#include <hip/hip_bf16.h>

// ---------------------------------------------------------------------------
// Compile-time construction of the 28x8 DWT composition matrix M:
//   y[k] = sum_j M[k][j] * patch[j],  k = [aa(7), ad(7), dd(7), da(7)]
// exactly matching pywt dwt mode='symmetric' applied twice (n=8 then n=7).
// ---------------------------------------------------------------------------
struct M28x8 { float m[28][8]; };

constexpr double DLO[8] = {-0.010597401784997278, 0.032883011666982945,
                            0.030841381835986965, -0.18703481171888114,
                           -0.02798376941698385,   0.6308807679295904,
                            0.7148465705525415,    0.23037781330885523};
constexpr double DHI[8] = {-0.23037781330885523,   0.7148465705525415,
                           -0.6308807679295904,   -0.02798376941698385,
                            0.18703481171888114,   0.030841381835986965,
                           -0.032883011666982945, -0.010597401784997278};

constexpr void dwt_c(const double* x, int n, double* lo, double* hi) {
    int out_len = (n + 7) / 2;
    for (int i = 0; i < out_len; ++i) {
        double a = 0.0, d = 0.0;
        for (int j = 0; j < 8; ++j) {
            int q = 2 * i + j - 6;
            if (q < 0) q = -q - 1;
            if (q >= n) q = 2 * n - 1 - q;
            a += DLO[7 - j] * x[q];
            d += DHI[7 - j] * x[q];
        }
        lo[i] = a; hi[i] = d;
    }
}

constexpr M28x8 build_M() {
    M28x8 R{};
    for (int j = 0; j < 8; ++j) {
        double x[8] = {0,0,0,0,0,0,0,0};
        x[j] = 1.0;
        double cA[7] = {}, cD[7] = {};
        dwt_c(x, 8, cA, cD);
        double aa[7] = {}, ad[7] = {}, da[7] = {}, dd[7] = {};
        dwt_c(cA, 7, aa, ad);
        dwt_c(cD, 7, da, dd);
        for (int i = 0; i < 7; ++i) {
            R.m[i][j]      = (float)aa[i];
            R.m[7 + i][j]  = (float)ad[i];
            R.m[14 + i][j] = (float)dd[i];   // dd before da in concat
            R.m[21 + i][j] = (float)da[i];
        }
    }
    return R;
}

__constant__ M28x8 g_M = build_M();

// ---------------------------------------------------------------------------
// WfT[i][o] = sum_k W[o, c*28+k] * M[k][j],  i = c*8+j  -> 24 x 128 floats.
// Transposed layout: inner o-loop reads 32 consecutive floats at
// compile-time offsets -> s_load_dwordx16 bursts in the main kernel.
// ---------------------------------------------------------------------------
__global__ void wfold_kernel(const float* __restrict__ W, float* __restrict__ WfT) {
    int idx = blockIdx.x * blockDim.x + threadIdx.x;
    if (idx >= 24 * 128) return;
    int o = idx & 127;
    int i = idx >> 7;        // 0..23
    int c = i >> 3;
    int j = i & 7;
    const float* wr = W + o * 84 + c * 28;
    float acc = 0.f;
#pragma unroll
    for (int k = 0; k < 28; ++k) acc += wr[k] * g_M.m[k][j];
    WfT[i * 128 + o] = acc;
}

// ---------------------------------------------------------------------------
// Main kernel (round-4).
//   out[b, v*1024 + p, o] = sum_i WfT[i][o] * xw[i]   (xw = 24-float window)
//
// Structure (fixes round-3's two measured problems: 1-block/CU occupancy and
// 64-line scattered stores, while keeping its lane-owns-pair compute):
//   * PT=32 -> slab 40.8 KB; slab + staging = 77.7 KB -> 2 blocks/CU,
//     8 waves/CU (round 3: 78 KB slab -> 1 block, 5 waves).
//   * lane owns pair (v, pl): wave-iter = 2 v x 32 pl. Weights wave-uniform
//     (scalar cache); acc[32] per o-chunk = 32 independent FMA chains.
//   * coalesced stores via per-wave LDS transpose tile (64 rows x 32 floats,
//     ROW STRIDE 36 words): the +4 pad makes both row-major b128 writes and
//     transposed b128 reads tile all 32 banks (optimal 8-phase). Tile is
//     wave-private -> no __syncthreads in the loop; intra-wave ordering via
//     s_waitcnt lgkmcnt(0) + sched_barrier(0) fences.
//   * store instr = 8 pairs x 128 B segments (16 lines) vs round-3's 64
//     scattered 16 B lines.
//   * v=24 half-iter handled by "wave 3" with read-rounds capped at 4;
//     block-parity flips the wave->v map to balance SIMD load.
// ---------------------------------------------------------------------------
#define PT     32
#define TTL    132                 // logical t-values per block (4*PT+4)
#define TTS    136                 // padded slab row stride (words, 16B-aligned)
#define SLABW  (3 * 25 * TTS)      // 10200 words = 40.8 KB
#define STROW  36                  // staging row stride (words, 144 B)
#define STAGEW (64 * STROW)        // 2304 words per wave

__global__ __launch_bounds__(256, 2) void wave_kernel(const float* __restrict__ x,
                                                      const float* __restrict__ WfT,
                                                      float* __restrict__ out) {
    __shared__ float s_x[SLABW];
    __shared__ float s_st[4 * STAGEW];
    const int tile = blockIdx.x;        // 0..31
    const int b    = blockIdx.y;        // 0..31
    const int t0   = tile * (4 * PT);
    const int tid  = threadIdx.x;

    // stage global -> LDS slab [c][v][t-pad] (contiguous per c-segment)
    for (int lin = tid; lin < 3 * 25 * TTL; lin += 256) {
        int v  = lin % 25;
        int r  = lin / 25;        // c*TTL + tt
        int tt = r % TTL;
        int c  = r / TTL;
        int t  = t0 + tt;
        if (t > 4095) t = 4095;   // edge padding (PAD=4)
        s_x[(c * 25 + v) * TTS + tt] = x[((b * 3 + c) * 4096 + t) * 25 + v];
    }
    __syncthreads();

    const int lane = tid & 63;
    const int wv   = tid >> 6;          // 0..3
    // balance the extra half-iter (v=24) across SIMDs by block parity
    const int wq   = ((tile + b) & 1) ? (3 - wv) : wv;
    const int vh   = lane >> 5;         // 0/1: which v of the pair
    const int pl   = lane & 31;         // p within tile
    const int g    = lane >> 3;         // read-round: pair sub-index
    const int q    = lane & 7;          // read-round: o-quad
    float* tb = s_st + wv * STAGEW;     // wave-private staging tile

    const int niter = (wq == 3) ? 4 : 3;
    for (int it = 0; it < niter; ++it) {
        const int v0   = 6 * wq + 2 * it;     // wq=3,it=3 -> v0=24 (half)
        const bool half = (v0 == 24);
        int vv = v0 + vh;
        if (vv > 24) vv = 24;                 // masked lanes: duplicate v=24

        // per-lane 24-float window (conflict-free contiguous b128 reads)
        float xw[24];
#pragma unroll
        for (int c = 0; c < 3; ++c) {
            const float4* wp = (const float4*)(s_x + (c * 25 + vv) * TTS + 4 * pl);
            float4 xa = wp[0];
            float4 xb = wp[1];
            xw[c*8+0] = xa.x; xw[c*8+1] = xa.y; xw[c*8+2] = xa.z; xw[c*8+3] = xa.w;
            xw[c*8+4] = xb.x; xw[c*8+5] = xb.y; xw[c*8+6] = xb.z; xw[c*8+7] = xb.w;
        }

        const long obase = ((long)(b * 25600 + v0 * 1024 + tile * PT)) * 128;
        const int  nr    = half ? 4 : 8;

        for (int ch = 0; ch < 4; ++ch) {      // 4 o-chunks of 32
            float acc[32];
#pragma unroll
            for (int oq = 0; oq < 32; ++oq) acc[oq] = 0.f;

            const float* wt = WfT + ch * 32;  // uniform -> scalar loads
#pragma unroll
            for (int i = 0; i < 24; ++i) {
#pragma unroll
                for (int oq = 0; oq < 32; ++oq)
                    acc[oq] += wt[i * 128 + oq] * xw[i];
            }

            // stage: lane writes its own row (stride-36 pad -> bank-optimal)
            float* myrow = tb + lane * STROW;
#pragma unroll
            for (int qq = 0; qq < 8; ++qq) {
                float4 st = {acc[4*qq+0], acc[4*qq+1], acc[4*qq+2], acc[4*qq+3]};
                *(float4*)(myrow + 4 * qq) = st;
            }
            asm volatile("s_waitcnt lgkmcnt(0)" ::: "memory");
            __builtin_amdgcn_sched_barrier(0);

            // transpose read + coalesced store: 8 pairs x 128 B per instr
            for (int r = 0; r < nr; ++r) {
                const float4 val = *(const float4*)(tb + (r * 8 + g) * STROW + 4 * q);
                const int orow = (r >> 2) * 1024 + (r & 3) * 8 + g;
                *(float4*)(out + obase + (long)orow * 128 + ch * 32 + 4 * q) = val;
            }
            asm volatile("s_waitcnt lgkmcnt(0)" ::: "memory");
            __builtin_amdgcn_sched_barrier(0);
        }
    }
}

extern "C" void kernel_launch(void* const* d_in, const int* in_sizes, int n_in,
                              void* d_out, int out_size, void* d_ws, size_t ws_size,
                              hipStream_t stream) {
    const float* x = (const float*)d_in[0];   // (32, 3, 4096, 25) fp32
    const float* W = (const float*)d_in[1];   // (128, 84) fp32
    float* out = (float*)d_out;               // (32, 25600, 128) fp32
    float* WfT = (float*)d_ws;                // 3072 floats scratch

    hipLaunchKernelGGL(wfold_kernel, dim3(12), dim3(256), 0, stream, W, WfT);
    hipLaunchKernelGGL(wave_kernel, dim3(32, 32), dim3(256), 0, stream, x, WfT, out);
}